// Round 12
// baseline (363.223 us; speedup 1.0000x reference)
//
#include <hip/hip_runtime.h>
#include <hip/hip_bf16.h>

#define H 8
#define HD 32
#define DD 256
#define NEG_SLOPE 0.2f
#define EPB 4096    // edges per sort block (256 thr x 16)
#define NBMAX 256   // coarse buckets (dst>>8; valid for N <= 65536)

typedef short bf16x8 __attribute__((ext_vector_type(8)));
typedef float f32x4 __attribute__((ext_vector_type(4)));

__device__ __forceinline__ unsigned short f2bf(float f) {
    unsigned int u = __float_as_uint(f);
    unsigned int r = (u + 0x7fffu + ((u >> 16) & 1u)) >> 16;
    return (unsigned short)r;
}
__device__ __forceinline__ float bf2f(unsigned short b) {
    return __uint_as_float(((unsigned int)b) << 16);
}

#define GLOAD_LDS16(g, s)                                                        \
    __builtin_amdgcn_global_load_lds((const __attribute__((address_space(1))) void*)(g), \
                                     (__attribute__((address_space(3))) void*)(s), 16, 0, 0)

// exclusive scan of one int per thread across a 256-thread block.
// wp: 4-int LDS scratch. Two barriers inside; safe to call repeatedly.
__device__ __forceinline__ int block_excl_scan(int v, int* wp) {
    int tid = threadIdx.x, lane = tid & 63, wv = tid >> 6;
    int s = v;
#pragma unroll
    for (int off = 1; off < 64; off <<= 1) {
        int t = __shfl_up(s, off, 64);
        if (lane >= off) s += t;
    }
    __syncthreads();  // protect wp reuse across calls
    if (lane == 63) wp[wv] = s;
    __syncthreads();
    int wbase = 0;
#pragma unroll
    for (int i = 0; i < 4; i++) wbase += (i < wv) ? wp[i] : 0;
    return wbase + s - v;
}

// ---------------- prep: S1 coarse-hist (no global atomics) + transposes + conv
// blocks [0,SB): LDS histogram of dst>>8 over 4096 edges -> plain store of
// per-(block,bucket) counts to blockBase. Zero global atomics.
// [SB,SB+768) weight transposes, rest x->bf16.
__global__ __launch_bounds__(256) void prep(const float* __restrict__ x, unsigned short* __restrict__ xb,
                                            const float* __restrict__ W, unsigned short* __restrict__ Wt,
                                            const float* __restrict__ W1, unsigned short* __restrict__ W1t,
                                            const float* __restrict__ W2, unsigned short* __restrict__ W2t,
                                            const int* __restrict__ ei, int* __restrict__ blockBase,
                                            int N, int n4, int E, int SB) {
    __shared__ int lhist[NBMAX];
    int b = blockIdx.x;
    int tid = threadIdx.x;
    if (b < SB) {
        lhist[tid] = 0;
        __syncthreads();
        int e0 = b * EPB;
#pragma unroll
        for (int i = 0; i < 16; i++) {
            int e = e0 + i * 256 + tid;
            if (e < E) atomicAdd(&lhist[((unsigned)ei[E + e]) >> 8], 1);
        }
        __syncthreads();
        blockBase[b * NBMAX + tid] = lhist[tid];
    } else if (b < SB + 768) {
        int wb = b - SB;
        const float* src = (wb < 256) ? W : (wb < 512) ? W1 : W2;
        unsigned short* dst = (wb < 256) ? Wt : (wb < 512) ? W1t : W2t;
        int i = (wb & 255) * 256 + tid;
        int n = i >> 8, k = i & 255;
        dst[i] = f2bf(src[k * 256 + n]);
    } else {
        int i = (b - SB - 768) * 256 + tid;
        if (i < n4) {
            float4 v = ((const float4*)x)[i];
            ushort4 o;
            o.x = f2bf(v.x); o.y = f2bf(v.y); o.z = f2bf(v.z); o.w = f2bf(v.w);
            ((ushort4*)xb)[i] = o;
        }
    }
}

// ---------------- S3: scatter edges to bucket-grouped tmp --------------------
// Each block recomputes bucket totals + its own per-bucket base from the raw
// blockBase counts (coalesced reads, no global atomics, no scan kernel).
__global__ __launch_bounds__(256) void bucket_scatter(const int* __restrict__ ei,
                                                      const int* __restrict__ blockBase,
                                                      unsigned int* __restrict__ tmp, int E, int SB) {
    __shared__ int myb[NBMAX];
    __shared__ int lrank[NBMAX];
    __shared__ int wp[4];
    int b = blockIdx.x;
    int tid = threadIdx.x;
    int t = 0, pb = 0;
    for (int bb = 0; bb < SB; bb++) {
        int c = blockBase[bb * NBMAX + tid];  // coalesced: lanes read consecutive
        t += c;
        if (bb < b) pb += c;
    }
    int excl = block_excl_scan(t, wp);  // bucket-global exclusive base
    myb[tid] = excl + pb;
    lrank[tid] = 0;
    __syncthreads();
    int e0 = b * EPB;
#pragma unroll
    for (int i = 0; i < 16; i++) {
        int e = e0 + i * 256 + tid;
        if (e < E) {
            int s = ei[e];
            unsigned d = (unsigned)ei[E + e];
            int k = d >> 8;
            int r = atomicAdd(&lrank[k], 1);
            tmp[myb[k] + r] = ((d & 255u) << 24) | (unsigned)s;
        }
    }
}

// ---------------- fused GEMM + appended bucket_csr blocks --------------------
// blocks [0,gB): BARRIER-FREE GEMM (full A-tile LDS once; B direct from L2).
// blocks [gB,gB+NB) (ATTN only): per-bucket dest-CSR from tmp -> compact
// src_sorted/rowPtr/cnt. Hides under the GEMM tail.
template <bool ATTN, bool PHASE2>
__global__ __launch_bounds__(256) void gemm_fused(
    const unsigned short* __restrict__ A,
    const unsigned short* __restrict__ B1t, const float* __restrict__ b1,
    const unsigned short* __restrict__ B2t, const float* __restrict__ b2,
    void* __restrict__ Cout, int M,
    const float* __restrict__ att_s, const float* __restrict__ att_d,
    float* __restrict__ a_srcO, float* __restrict__ a_dstO,
    const int* __restrict__ blockBase, const unsigned int* __restrict__ tmp,
    int* __restrict__ src_sorted, int* __restrict__ rowPtr, int* __restrict__ cnt,
    int N, int SB, int gB) {
    __shared__ __align__(16) unsigned short Als[16384];  // 32KB full-K A (csr: int scratch)
    __shared__ __align__(16) unsigned short t1ls[PHASE2 ? 64 * 280 : 8];  // 35KB, stride 280

    const int tid = threadIdx.x;

    if constexpr (ATTN) {
        if ((int)blockIdx.x >= gB) {
            // ---- bucket_csr for bucket k ----
            int k = (int)blockIdx.x - gB;
            int* L = (int*)Als;
            int* exclArr = L;            // [256]
            int* totArr = L + 256;       // [256]
            int* dh = L + 512;           // [256]
            int* dbase = L + 768;        // [256]
            int* dr = L + 1024;          // [256]
            int* wp = L + 1280;          // [4]
            int t = 0;
            for (int b = 0; b < SB; b++) t += blockBase[b * NBMAX + tid];
            int excl = block_excl_scan(t, wp);
            exclArr[tid] = excl;
            totArr[tid] = t;
            dh[tid] = 0;
            dr[tid] = 0;
            __syncthreads();
            int base = exclArr[k];
            int M_ = totArr[k];
            for (int i = tid; i < M_; i += 256) atomicAdd(&dh[tmp[base + i] >> 24], 1);
            __syncthreads();
            int c = dh[tid];
            int dexcl = block_excl_scan(c, wp);
            int d = (k << 8) + tid;
            if (d < N) { cnt[d] = c; rowPtr[d] = base + dexcl; }
            dbase[tid] = dexcl;
            __syncthreads();
            for (int i = tid; i < M_; i += 256) {
                unsigned p = tmp[base + i];
                int dl = p >> 24;
                int r = atomicAdd(&dr[dl], 1);
                src_sorted[base + dbase[dl] + r] = (int)(p & 0xFFFFFFu);
            }
            return;
        }
    }

    const int l = tid & 63;
    const int w = tid >> 6;
    const int r16 = l & 15, q0 = l >> 4;
    const int row0 = blockIdx.x * 64;

#pragma unroll
    for (int k = 0; k < 8; k++) {
        int c = k * 256 + tid;
        const unsigned short* g = A + (size_t)min(row0 + (c & 63), M - 1) * DD + (c >> 6) * 8;
        GLOAD_LDS16(g, &Als[c * 8]);
    }
    __syncthreads();

    f32x4 zero = {0.f, 0.f, 0.f, 0.f};
    f32x4 acc[4][4];
#pragma unroll
    for (int i = 0; i < 4; i++)
#pragma unroll
        for (int j = 0; j < 4; j++) acc[i][j] = zero;

#pragma unroll
    for (int kk = 0; kk < 4; kk++) {
#pragma unroll
        for (int t = 0; t < 2; t++) {
            const int qq = kk * 8 + t * 4 + q0;
            bf16x8 af[4], bf[4];
#pragma unroll
            for (int j = 0; j < 4; j++)
                bf[j] = *(const bf16x8*)&B1t[(size_t)(w * 64 + j * 16 + r16) * DD + qq * 8];
#pragma unroll
            for (int i = 0; i < 4; i++)
                af[i] = *(const bf16x8*)&Als[(qq * 64 + i * 16 + r16) * 8];
#pragma unroll
            for (int i = 0; i < 4; i++)
#pragma unroll
                for (int j = 0; j < 4; j++)
                    acc[i][j] = __builtin_amdgcn_mfma_f32_16x16x32_bf16(af[i], bf[j], acc[i][j], 0, 0, 0);
        }
    }

    if (!PHASE2) {
        float aws0, aws1, aws2, aws3, awd0, awd1, awd2, awd3;
        int hA = 0, hB = 0;
        if (ATTN) {
            hA = w * 2; hB = hA + 1;
            aws0 = att_s[hA * HD + r16];
            aws1 = att_s[hA * HD + 16 + r16];
            aws2 = att_s[hB * HD + r16];
            aws3 = att_s[hB * HD + 16 + r16];
            awd0 = att_d[hA * HD + r16];
            awd1 = att_d[hA * HD + 16 + r16];
            awd2 = att_d[hB * HD + r16];
            awd3 = att_d[hB * HD + 16 + r16];
        }
#pragma unroll
        for (int i = 0; i < 4; i++) {
#pragma unroll
            for (int r = 0; r < 4; r++) {
                int row = row0 + i * 16 + q0 * 4 + r;
                if (row < M) {
#pragma unroll
                    for (int j = 0; j < 4; j++) {
                        int col = w * 64 + j * 16 + r16;
                        ((unsigned short*)Cout)[(size_t)row * DD + col] = f2bf(acc[i][j][r]);
                    }
                }
                if (ATTN) {
                    float v0 = acc[i][0][r], v1 = acc[i][1][r];
                    float v2 = acc[i][2][r], v3 = acc[i][3][r];
                    float ps0 = v0 * aws0 + v1 * aws1;
                    float ps1 = v2 * aws2 + v3 * aws3;
                    float pd0 = v0 * awd0 + v1 * awd1;
                    float pd1 = v2 * awd2 + v3 * awd3;
#pragma unroll
                    for (int m = 1; m < 16; m <<= 1) {
                        ps0 += __shfl_xor(ps0, m, 64);
                        ps1 += __shfl_xor(ps1, m, 64);
                        pd0 += __shfl_xor(pd0, m, 64);
                        pd1 += __shfl_xor(pd1, m, 64);
                    }
                    if (r16 == 0 && row < M) {
                        a_srcO[row * H + hA] = ps0;
                        a_srcO[row * H + hB] = ps1;
                        a_dstO[row * H + hA] = pd0;
                        a_dstO[row * H + hB] = pd1;
                    }
                }
            }
        }
    } else {
        float bb1[4];
#pragma unroll
        for (int j = 0; j < 4; j++) bb1[j] = b1[w * 64 + j * 16 + r16];
#pragma unroll
        for (int i = 0; i < 4; i++)
#pragma unroll
            for (int r = 0; r < 4; r++) {
                int rl = i * 16 + q0 * 4 + r;
#pragma unroll
                for (int j = 0; j < 4; j++) {
                    float v = fmaxf(acc[i][j][r] + bb1[j], 0.f);
                    t1ls[rl * 280 + w * 64 + j * 16 + r16] = f2bf(v);
                }
            }
        __syncthreads();

#pragma unroll
        for (int i = 0; i < 4; i++)
#pragma unroll
            for (int j = 0; j < 4; j++) acc[i][j] = zero;

#pragma unroll
        for (int kk = 0; kk < 4; kk++) {
#pragma unroll
            for (int t = 0; t < 2; t++) {
                const int qq = kk * 8 + t * 4 + q0;
                bf16x8 af[4], bf[4];
#pragma unroll
                for (int j = 0; j < 4; j++)
                    bf[j] = *(const bf16x8*)&B2t[(size_t)(w * 64 + j * 16 + r16) * DD + qq * 8];
#pragma unroll
                for (int i = 0; i < 4; i++)
                    af[i] = *(const bf16x8*)&t1ls[(i * 16 + r16) * 280 + qq * 8];
#pragma unroll
                for (int i = 0; i < 4; i++)
#pragma unroll
                    for (int j = 0; j < 4; j++)
                        acc[i][j] = __builtin_amdgcn_mfma_f32_16x16x32_bf16(af[i], bf[j], acc[i][j], 0, 0, 0);
            }
        }

        float bb2[4];
#pragma unroll
        for (int j = 0; j < 4; j++) bb2[j] = b2[w * 64 + j * 16 + r16];
#pragma unroll
        for (int i = 0; i < 4; i++)
#pragma unroll
            for (int r = 0; r < 4; r++) {
                int row = row0 + i * 16 + q0 * 4 + r;
                if (row < M) {
#pragma unroll
                    for (int j = 0; j < 4; j++) {
                        int col = w * 64 + j * 16 + r16;
                        ((float*)Cout)[(size_t)row * DD + col] = acc[i][j][r] + bb2[j];
                    }
                }
            }
    }
}

// ---------------- fused softmax-aggregate + bias + residual + LN -------------
// Compact CSR: row n occupies src_sorted[rowPtr[n] .. rowPtr[n]+cnt[n]).
__global__ __launch_bounds__(256) void aggregate_ln(
    const unsigned short* __restrict__ xp, const unsigned short* __restrict__ x_bf,
    const float* __restrict__ a_src, const float* __restrict__ a_dst,
    const int* __restrict__ rowPtr, const int* __restrict__ cnt,
    const int* __restrict__ src_sorted,
    const float* __restrict__ bias, const float* __restrict__ ln_g,
    const float* __restrict__ ln_b, unsigned short* __restrict__ hn, int N) {
    int wave = threadIdx.x >> 6;
    int lane = threadIdx.x & 63;
    int n = blockIdx.x * 4 + wave;
    if (n >= N) return;
    int h = lane >> 3;

    float adst = a_dst[n * H + h];
    float e0 = a_src[n * H + h] + adst;
    e0 = (e0 > 0.f) ? e0 : NEG_SLOPE * e0;
    float ex = __expf(e0);
    ushort4 u = *(const ushort4*)(xp + (size_t)n * DD + lane * 4);
    float acc0 = ex * bf2f(u.x), acc1 = ex * bf2f(u.y);
    float acc2 = ex * bf2f(u.z), acc3 = ex * bf2f(u.w);
    float denom = ex;

    int beg = rowPtr[n];
    int end = beg + cnt[n];
    int i = beg;
    for (; i + 7 < end; i += 8) {
        int s[8];
        float es[8];
        ushort4 uu[8];
#pragma unroll
        for (int k = 0; k < 8; k++) s[k] = src_sorted[i + k];
#pragma unroll
        for (int k = 0; k < 8; k++) es[k] = a_src[s[k] * H + h];
#pragma unroll
        for (int k = 0; k < 8; k++) uu[k] = *(const ushort4*)(xp + (size_t)s[k] * DD + lane * 4);
#pragma unroll
        for (int k = 0; k < 8; k++) {
            float e = es[k] + adst;
            e = (e > 0.f) ? e : NEG_SLOPE * e;
            float wk = __expf(e);
            acc0 += wk * bf2f(uu[k].x);
            acc1 += wk * bf2f(uu[k].y);
            acc2 += wk * bf2f(uu[k].z);
            acc3 += wk * bf2f(uu[k].w);
            denom += wk;
        }
    }
    for (; i < end; i++) {
        int s0 = src_sorted[i];
        float es0 = a_src[s0 * H + h];
        ushort4 u0 = *(const ushort4*)(xp + (size_t)s0 * DD + lane * 4);
        float e0a = es0 + adst;
        e0a = (e0a > 0.f) ? e0a : NEG_SLOPE * e0a;
        float w0 = __expf(e0a);
        acc0 += w0 * bf2f(u0.x);
        acc1 += w0 * bf2f(u0.y);
        acc2 += w0 * bf2f(u0.z);
        acc3 += w0 * bf2f(u0.w);
        denom += w0;
    }
    float inv = 1.f / (denom + 1e-16f);
    float4 bb = *(const float4*)(bias + lane * 4);
    ushort4 xr = *(const ushort4*)(x_bf + (size_t)n * DD + lane * 4);
    float r0 = acc0 * inv + bb.x + bf2f(xr.x);
    float r1 = acc1 * inv + bb.y + bf2f(xr.y);
    float r2 = acc2 * inv + bb.z + bf2f(xr.z);
    float r3 = acc3 * inv + bb.w + bf2f(xr.w);

    float s = r0 + r1 + r2 + r3;
#pragma unroll
    for (int m = 1; m < 64; m <<= 1) s += __shfl_xor(s, m, 64);
    float mu = s * (1.f / 256.f);
    float d0 = r0 - mu, d1 = r1 - mu, d2 = r2 - mu, d3 = r3 - mu;
    float qv = d0 * d0 + d1 * d1 + d2 * d2 + d3 * d3;
#pragma unroll
    for (int m = 1; m < 64; m <<= 1) qv += __shfl_xor(qv, m, 64);
    float rstd = rsqrtf(qv * (1.f / 256.f) + 1e-5f);
    float4 g = *(const float4*)(ln_g + lane * 4);
    float4 b = *(const float4*)(ln_b + lane * 4);
    ushort4 o;
    o.x = f2bf(d0 * rstd * g.x + b.x);
    o.y = f2bf(d1 * rstd * g.y + b.y);
    o.z = f2bf(d2 * rstd * g.z + b.z);
    o.w = f2bf(d3 * rstd * g.w + b.w);
    *(ushort4*)(hn + (size_t)n * DD + lane * 4) = o;
}

// ---------------- launch ------------------------------------------------------
extern "C" void kernel_launch(void* const* d_in, const int* in_sizes, int n_in,
                              void* d_out, int out_size, void* d_ws, size_t ws_size,
                              hipStream_t stream) {
    const float* x = (const float*)d_in[0];
    const int* edge_index = (const int*)d_in[1];
    const float* W = (const float*)d_in[3];
    const float* att_src = (const float*)d_in[4];
    const float* att_dst = (const float*)d_in[5];
    const float* bias = (const float*)d_in[6];
    const float* ln_g = (const float*)d_in[7];
    const float* ln_b = (const float*)d_in[8];
    const float* W1 = (const float*)d_in[9];
    const float* b1 = (const float*)d_in[10];
    const float* W2 = (const float*)d_in[11];
    const float* b2 = (const float*)d_in[12];

    const int N = in_sizes[0] / DD;
    const int E = in_sizes[1] / 2;

    // workspace carve-up
    char* p = (char*)d_ws;
    auto carve = [&](size_t bytes) {
        char* r = p;
        p += (bytes + 255) & ~(size_t)255;
        return r;
    };
    unsigned short* x_bf = (unsigned short*)carve((size_t)N * DD * 2);
    unsigned short* xp_bf = (unsigned short*)carve((size_t)N * DD * 2);
    unsigned short* hn_bf = (unsigned short*)carve((size_t)N * DD * 2);
    float* a_src = (float*)carve((size_t)N * H * 4);
    float* a_dst = (float*)carve((size_t)N * H * 4);
    int* rowPtr = (int*)carve((size_t)N * 4);
    int* cnt = (int*)carve((size_t)N * 4);
    unsigned int* tmp = (unsigned int*)carve((size_t)E * 4);  // bucket-grouped packed
    int* src_sorted = (int*)carve((size_t)E * 4);             // compact CSR payload
    int* blockBase = (int*)carve((size_t)((E + EPB - 1) / EPB) * NBMAX * 4);
    unsigned short* Wt = (unsigned short*)carve(65536 * 2);
    unsigned short* W1t = (unsigned short*)carve(65536 * 2);
    unsigned short* W2t = (unsigned short*)carve(65536 * 2);

    const int n4 = N * DD / 4;
    const int SB = (E + EPB - 1) / EPB;  // sort blocks (196)
    const int NB = (N + 255) >> 8;       // dest buckets (196)

    // 1. prep: S1 coarse-hist (plain stores) + weight transposes + x->bf16
    int prep_blocks = SB + 768 + (n4 + 255) / 256;
    prep<<<prep_blocks, 256, 0, stream>>>(x, x_bf, W, Wt, W1, W1t, W2, W2t,
                                          edge_index, blockBase, N, n4, E, SB);

    // 2. bucket-scatter (self-computed bases; no scan kernel, no global atomics)
    bucket_scatter<<<SB, 256, 0, stream>>>(edge_index, blockBase, tmp, E, SB);

    const int gblocks = (N + 63) / 64;

    // 3. xp = x @ W + attn scores, with bucket_csr blocks appended (overlap)
    gemm_fused<true, false><<<gblocks + NB, 256, 0, stream>>>(
        x_bf, Wt, nullptr, nullptr, nullptr, xp_bf, N, att_src, att_dst, a_src, a_dst,
        blockBase, tmp, src_sorted, rowPtr, cnt, N, SB, gblocks);

    // 4. fused aggregate + LN (bf16 out, compact CSR)
    aggregate_ln<<<(N + 3) / 4, 256, 0, stream>>>(xp_bf, x_bf, a_src, a_dst, rowPtr, cnt,
                                                  src_sorted, bias, ln_g, ln_b, hn_bf, N);

    // 5. fused FFN: out = relu(hn@W1+b1)@W2 + b2
    gemm_fused<false, true><<<gblocks, 256, 0, stream>>>(
        hn_bf, W1t, b1, W2t, b2, d_out, N, nullptr, nullptr, nullptr, nullptr,
        nullptr, nullptr, nullptr, nullptr, nullptr, 0, 0, gblocks);
}

// Round 13
// 331.130 us; speedup vs baseline: 1.0969x; 1.0969x over previous
//
#include <hip/hip_runtime.h>
#include <hip/hip_bf16.h>

#define H 8
#define HD 32
#define DD 256
#define NEG_SLOPE 0.2f
#define EPB 4096    // edges per sort block (256 thr x 16)
#define NBMAX 256   // coarse buckets (dst>>8; valid for N <= 65536)

typedef short bf16x8 __attribute__((ext_vector_type(8)));
typedef float f32x4 __attribute__((ext_vector_type(4)));

__device__ __forceinline__ unsigned short f2bf(float f) {
    unsigned int u = __float_as_uint(f);
    unsigned int r = (u + 0x7fffu + ((u >> 16) & 1u)) >> 16;
    return (unsigned short)r;
}
__device__ __forceinline__ float bf2f(unsigned short b) {
    return __uint_as_float(((unsigned int)b) << 16);
}

#define GLOAD_LDS16(g, s)                                                        \
    __builtin_amdgcn_global_load_lds((const __attribute__((address_space(1))) void*)(g), \
                                     (__attribute__((address_space(3))) void*)(s), 16, 0, 0)

// ---------------- zero bucket counters (256 ints, 1 block) -------------------
__global__ __launch_bounds__(256) void zero_gc(int* __restrict__ gc) {
    gc[threadIdx.x] = 0;
}

// ---------------- prep: S1 coarse-hist (LDS) + transposes + conv x -----------
// blocks [0,SB): per-block LDS histogram of dst>>8 over 4096 edges, then ONE
// global atomic per nonzero bucket to reserve space (blockBase). 38k atomics
// total vs 800k. [SB,SB+768) weight transposes, rest x->bf16.
__global__ __launch_bounds__(256) void prep(const float* __restrict__ x, unsigned short* __restrict__ xb,
                                            const float* __restrict__ W, unsigned short* __restrict__ Wt,
                                            const float* __restrict__ W1, unsigned short* __restrict__ W1t,
                                            const float* __restrict__ W2, unsigned short* __restrict__ W2t,
                                            const int* __restrict__ ei, int* __restrict__ gc,
                                            int* __restrict__ blockBase, int N, int n4, int E, int SB) {
    __shared__ int lhist[NBMAX];
    int b = blockIdx.x;
    int tid = threadIdx.x;
    if (b < SB) {
        lhist[tid] = 0;
        __syncthreads();
        int e0 = b * EPB;
#pragma unroll
        for (int i = 0; i < 16; i++) {
            int e = e0 + i * 256 + tid;
            if (e < E) atomicAdd(&lhist[((unsigned)ei[E + e]) >> 8], 1);
        }
        __syncthreads();
        int c = lhist[tid];
        blockBase[b * NBMAX + tid] = c ? atomicAdd(&gc[tid], c) : 0;
    } else if (b < SB + 768) {
        int wb = b - SB;
        const float* src = (wb < 256) ? W : (wb < 512) ? W1 : W2;
        unsigned short* dst = (wb < 256) ? Wt : (wb < 512) ? W1t : W2t;
        int i = (wb & 255) * 256 + tid;
        int n = i >> 8, k = i & 255;
        dst[i] = f2bf(src[k * 256 + n]);
    } else {
        int i = (b - SB - 768) * 256 + tid;
        if (i < n4) {
            float4 v = ((const float4*)x)[i];
            ushort4 o;
            o.x = f2bf(v.x); o.y = f2bf(v.y); o.z = f2bf(v.z); o.w = f2bf(v.w);
            ((ushort4*)xb)[i] = o;
        }
    }
}

// ---------------- S2: exclusive scan of 256 bucket totals (1 wave) -----------
__global__ __launch_bounds__(64) void scan_gc(const int* __restrict__ gc, int* __restrict__ bb) {
    int lane = threadIdx.x;
    int v[4], s = 0;
#pragma unroll
    for (int i = 0; i < 4; i++) { v[i] = gc[lane * 4 + i]; s += v[i]; }
    int sc = s;
#pragma unroll
    for (int off = 1; off < 64; off <<= 1) {
        int t = __shfl_up(sc, off, 64);
        if (lane >= off) sc += t;
    }
    int run = sc - s;  // exclusive prefix of this lane's group
#pragma unroll
    for (int i = 0; i < 4; i++) { bb[lane * 4 + i] = run; run += v[i]; }
}

// ---------------- S3: scatter edges to bucket-grouped tmp (atomic-free) ------
// same block/edge mapping as S1; rank recomputed via LDS; writes contiguous
// per-(block,bucket) ranges. pack = (d&255)<<24 | src  (src < 2^24).
__global__ __launch_bounds__(256) void bucket_scatter(const int* __restrict__ ei,
                                                      const int* __restrict__ bb,
                                                      const int* __restrict__ blockBase,
                                                      unsigned int* __restrict__ tmp, int E) {
    __shared__ int lrank[NBMAX];
    int b = blockIdx.x;
    int tid = threadIdx.x;
    lrank[tid] = 0;
    __syncthreads();
    int e0 = b * EPB;
#pragma unroll
    for (int i = 0; i < 16; i++) {
        int e = e0 + i * 256 + tid;
        if (e < E) {
            int s = ei[e];
            unsigned d = (unsigned)ei[E + e];
            int k = d >> 8;
            int r = atomicAdd(&lrank[k], 1);
            tmp[bb[k] + blockBase[b * NBMAX + k] + r] = ((d & 255u) << 24) | (unsigned)s;
        }
    }
}

// ---------------- S4: per-bucket dest-CSR (one block per bucket) -------------
// LDS hist of 256 dests + LDS scan + LDS re-rank -> compact src_sorted,
// rowPtr[d], cnt[d]. No global atomics.
__global__ __launch_bounds__(256) void bucket_csr(const unsigned int* __restrict__ tmp,
                                                  const int* __restrict__ bb, const int* __restrict__ gc,
                                                  int* __restrict__ src_sorted, int* __restrict__ rowPtr,
                                                  int* __restrict__ cnt, int N) {
    __shared__ int dh[NBMAX];
    __shared__ int dbase[NBMAX];
    __shared__ int dr[NBMAX];
    int k = blockIdx.x;
    int tid = threadIdx.x;
    int base = bb[k];
    int M = gc[k];
    dh[tid] = 0;
    dr[tid] = 0;
    __syncthreads();
    for (int i = tid; i < M; i += 256) atomicAdd(&dh[tmp[base + i] >> 24], 1);
    __syncthreads();
    int c = dh[tid];
    dbase[tid] = c;
    __syncthreads();
    // Hillis-Steele inclusive scan over 256 entries
    for (int off = 1; off < 256; off <<= 1) {
        int add = (tid >= off) ? dbase[tid - off] : 0;
        __syncthreads();
        dbase[tid] += add;
        __syncthreads();
    }
    int excl = dbase[tid] - c;
    int d = (k << 8) + tid;
    if (d < N) { cnt[d] = c; rowPtr[d] = base + excl; }
    __syncthreads();
    dbase[tid] = excl;  // reuse as exclusive-base table
    __syncthreads();
    for (int i = tid; i < M; i += 256) {
        unsigned p = tmp[base + i];
        int dl = p >> 24;
        int r = atomicAdd(&dr[dl], 1);
        src_sorted[base + dbase[dl] + r] = (int)(p & 0xFFFFFFu);
    }
}

// ---------------- fused GEMM: 64 rows x full 256 cols per block --------------
// BARRIER-FREE K-loop (R10 form): full A-tile in LDS once; B direct from L2.
template <bool ATTN, bool PHASE2>
__global__ __launch_bounds__(256) void gemm_fused(
    const unsigned short* __restrict__ A,
    const unsigned short* __restrict__ B1t, const float* __restrict__ b1,
    const unsigned short* __restrict__ B2t, const float* __restrict__ b2,
    void* __restrict__ Cout, int M,
    const float* __restrict__ att_s, const float* __restrict__ att_d,
    float* __restrict__ a_srcO, float* __restrict__ a_dstO) {
    __shared__ __align__(16) unsigned short Als[16384];  // 32KB full-K A
    __shared__ __align__(16) unsigned short t1ls[PHASE2 ? 64 * 280 : 8];  // 35KB, stride 280

    const int tid = threadIdx.x;
    const int l = tid & 63;
    const int w = tid >> 6;
    const int r16 = l & 15, q0 = l >> 4;
    const int row0 = blockIdx.x * 64;

#pragma unroll
    for (int k = 0; k < 8; k++) {
        int c = k * 256 + tid;
        const unsigned short* g = A + (size_t)min(row0 + (c & 63), M - 1) * DD + (c >> 6) * 8;
        GLOAD_LDS16(g, &Als[c * 8]);
    }
    __syncthreads();

    f32x4 zero = {0.f, 0.f, 0.f, 0.f};
    f32x4 acc[4][4];
#pragma unroll
    for (int i = 0; i < 4; i++)
#pragma unroll
        for (int j = 0; j < 4; j++) acc[i][j] = zero;

#pragma unroll
    for (int kk = 0; kk < 4; kk++) {
#pragma unroll
        for (int t = 0; t < 2; t++) {
            const int qq = kk * 8 + t * 4 + q0;
            bf16x8 af[4], bf[4];
#pragma unroll
            for (int j = 0; j < 4; j++)
                bf[j] = *(const bf16x8*)&B1t[(size_t)(w * 64 + j * 16 + r16) * DD + qq * 8];
#pragma unroll
            for (int i = 0; i < 4; i++)
                af[i] = *(const bf16x8*)&Als[(qq * 64 + i * 16 + r16) * 8];
#pragma unroll
            for (int i = 0; i < 4; i++)
#pragma unroll
                for (int j = 0; j < 4; j++)
                    acc[i][j] = __builtin_amdgcn_mfma_f32_16x16x32_bf16(af[i], bf[j], acc[i][j], 0, 0, 0);
        }
    }

    if (!PHASE2) {
        float aws0, aws1, aws2, aws3, awd0, awd1, awd2, awd3;
        int hA = 0, hB = 0;
        if (ATTN) {
            hA = w * 2; hB = hA + 1;
            aws0 = att_s[hA * HD + r16];
            aws1 = att_s[hA * HD + 16 + r16];
            aws2 = att_s[hB * HD + r16];
            aws3 = att_s[hB * HD + 16 + r16];
            awd0 = att_d[hA * HD + r16];
            awd1 = att_d[hA * HD + 16 + r16];
            awd2 = att_d[hB * HD + r16];
            awd3 = att_d[hB * HD + 16 + r16];
        }
#pragma unroll
        for (int i = 0; i < 4; i++) {
#pragma unroll
            for (int r = 0; r < 4; r++) {
                int row = row0 + i * 16 + q0 * 4 + r;
                if (row < M) {
#pragma unroll
                    for (int j = 0; j < 4; j++) {
                        int col = w * 64 + j * 16 + r16;
                        ((unsigned short*)Cout)[(size_t)row * DD + col] = f2bf(acc[i][j][r]);
                    }
                }
                if (ATTN) {
                    float v0 = acc[i][0][r], v1 = acc[i][1][r];
                    float v2 = acc[i][2][r], v3 = acc[i][3][r];
                    float ps0 = v0 * aws0 + v1 * aws1;
                    float ps1 = v2 * aws2 + v3 * aws3;
                    float pd0 = v0 * awd0 + v1 * awd1;
                    float pd1 = v2 * awd2 + v3 * awd3;
#pragma unroll
                    for (int m = 1; m < 16; m <<= 1) {
                        ps0 += __shfl_xor(ps0, m, 64);
                        ps1 += __shfl_xor(ps1, m, 64);
                        pd0 += __shfl_xor(pd0, m, 64);
                        pd1 += __shfl_xor(pd1, m, 64);
                    }
                    if (r16 == 0 && row < M) {
                        a_srcO[row * H + hA] = ps0;
                        a_srcO[row * H + hB] = ps1;
                        a_dstO[row * H + hA] = pd0;
                        a_dstO[row * H + hB] = pd1;
                    }
                }
            }
        }
    } else {
        float bb1[4];
#pragma unroll
        for (int j = 0; j < 4; j++) bb1[j] = b1[w * 64 + j * 16 + r16];
#pragma unroll
        for (int i = 0; i < 4; i++)
#pragma unroll
            for (int r = 0; r < 4; r++) {
                int rl = i * 16 + q0 * 4 + r;
#pragma unroll
                for (int j = 0; j < 4; j++) {
                    float v = fmaxf(acc[i][j][r] + bb1[j], 0.f);
                    t1ls[rl * 280 + w * 64 + j * 16 + r16] = f2bf(v);
                }
            }
        __syncthreads();

#pragma unroll
        for (int i = 0; i < 4; i++)
#pragma unroll
            for (int j = 0; j < 4; j++) acc[i][j] = zero;

#pragma unroll
        for (int kk = 0; kk < 4; kk++) {
#pragma unroll
            for (int t = 0; t < 2; t++) {
                const int qq = kk * 8 + t * 4 + q0;
                bf16x8 af[4], bf[4];
#pragma unroll
                for (int j = 0; j < 4; j++)
                    bf[j] = *(const bf16x8*)&B2t[(size_t)(w * 64 + j * 16 + r16) * DD + qq * 8];
#pragma unroll
                for (int i = 0; i < 4; i++)
                    af[i] = *(const bf16x8*)&t1ls[(i * 16 + r16) * 280 + qq * 8];
#pragma unroll
                for (int i = 0; i < 4; i++)
#pragma unroll
                    for (int j = 0; j < 4; j++)
                        acc[i][j] = __builtin_amdgcn_mfma_f32_16x16x32_bf16(af[i], bf[j], acc[i][j], 0, 0, 0);
            }
        }

        float bb2[4];
#pragma unroll
        for (int j = 0; j < 4; j++) bb2[j] = b2[w * 64 + j * 16 + r16];
#pragma unroll
        for (int i = 0; i < 4; i++)
#pragma unroll
            for (int r = 0; r < 4; r++) {
                int row = row0 + i * 16 + q0 * 4 + r;
                if (row < M) {
#pragma unroll
                    for (int j = 0; j < 4; j++) {
                        int col = w * 64 + j * 16 + r16;
                        ((float*)Cout)[(size_t)row * DD + col] = acc[i][j][r] + bb2[j];
                    }
                }
            }
    }
}

// ---------------- fused softmax-aggregate + bias + residual + LN -------------
// Compact CSR: row n occupies src_sorted[rowPtr[n] .. rowPtr[n]+cnt[n]).
__global__ __launch_bounds__(256) void aggregate_ln(
    const unsigned short* __restrict__ xp, const unsigned short* __restrict__ x_bf,
    const float* __restrict__ a_src, const float* __restrict__ a_dst,
    const int* __restrict__ rowPtr, const int* __restrict__ cnt,
    const int* __restrict__ src_sorted,
    const float* __restrict__ bias, const float* __restrict__ ln_g,
    const float* __restrict__ ln_b, unsigned short* __restrict__ hn, int N) {
    int wave = threadIdx.x >> 6;
    int lane = threadIdx.x & 63;
    int n = blockIdx.x * 4 + wave;
    if (n >= N) return;
    int h = lane >> 3;

    float adst = a_dst[n * H + h];
    float e0 = a_src[n * H + h] + adst;
    e0 = (e0 > 0.f) ? e0 : NEG_SLOPE * e0;
    float ex = __expf(e0);
    ushort4 u = *(const ushort4*)(xp + (size_t)n * DD + lane * 4);
    float acc0 = ex * bf2f(u.x), acc1 = ex * bf2f(u.y);
    float acc2 = ex * bf2f(u.z), acc3 = ex * bf2f(u.w);
    float denom = ex;

    int beg = rowPtr[n];
    int end = beg + cnt[n];
    int i = beg;
    for (; i + 7 < end; i += 8) {
        int s[8];
        float es[8];
        ushort4 uu[8];
#pragma unroll
        for (int k = 0; k < 8; k++) s[k] = src_sorted[i + k];
#pragma unroll
        for (int k = 0; k < 8; k++) es[k] = a_src[s[k] * H + h];
#pragma unroll
        for (int k = 0; k < 8; k++) uu[k] = *(const ushort4*)(xp + (size_t)s[k] * DD + lane * 4);
#pragma unroll
        for (int k = 0; k < 8; k++) {
            float e = es[k] + adst;
            e = (e > 0.f) ? e : NEG_SLOPE * e;
            float wk = __expf(e);
            acc0 += wk * bf2f(uu[k].x);
            acc1 += wk * bf2f(uu[k].y);
            acc2 += wk * bf2f(uu[k].z);
            acc3 += wk * bf2f(uu[k].w);
            denom += wk;
        }
    }
    for (; i < end; i++) {
        int s0 = src_sorted[i];
        float es0 = a_src[s0 * H + h];
        ushort4 u0 = *(const ushort4*)(xp + (size_t)s0 * DD + lane * 4);
        float e0a = es0 + adst;
        e0a = (e0a > 0.f) ? e0a : NEG_SLOPE * e0a;
        float w0 = __expf(e0a);
        acc0 += w0 * bf2f(u0.x);
        acc1 += w0 * bf2f(u0.y);
        acc2 += w0 * bf2f(u0.z);
        acc3 += w0 * bf2f(u0.w);
        denom += w0;
    }
    float inv = 1.f / (denom + 1e-16f);
    float4 bb = *(const float4*)(bias + lane * 4);
    ushort4 xr = *(const ushort4*)(x_bf + (size_t)n * DD + lane * 4);
    float r0 = acc0 * inv + bb.x + bf2f(xr.x);
    float r1 = acc1 * inv + bb.y + bf2f(xr.y);
    float r2 = acc2 * inv + bb.z + bf2f(xr.z);
    float r3 = acc3 * inv + bb.w + bf2f(xr.w);

    float s = r0 + r1 + r2 + r3;
#pragma unroll
    for (int m = 1; m < 64; m <<= 1) s += __shfl_xor(s, m, 64);
    float mu = s * (1.f / 256.f);
    float d0 = r0 - mu, d1 = r1 - mu, d2 = r2 - mu, d3 = r3 - mu;
    float qv = d0 * d0 + d1 * d1 + d2 * d2 + d3 * d3;
#pragma unroll
    for (int m = 1; m < 64; m <<= 1) qv += __shfl_xor(qv, m, 64);
    float rstd = rsqrtf(qv * (1.f / 256.f) + 1e-5f);
    float4 g = *(const float4*)(ln_g + lane * 4);
    float4 b = *(const float4*)(ln_b + lane * 4);
    ushort4 o;
    o.x = f2bf(d0 * rstd * g.x + b.x);
    o.y = f2bf(d1 * rstd * g.y + b.y);
    o.z = f2bf(d2 * rstd * g.z + b.z);
    o.w = f2bf(d3 * rstd * g.w + b.w);
    *(ushort4*)(hn + (size_t)n * DD + lane * 4) = o;
}

// ---------------- launch ------------------------------------------------------
extern "C" void kernel_launch(void* const* d_in, const int* in_sizes, int n_in,
                              void* d_out, int out_size, void* d_ws, size_t ws_size,
                              hipStream_t stream) {
    const float* x = (const float*)d_in[0];
    const int* edge_index = (const int*)d_in[1];
    const float* W = (const float*)d_in[3];
    const float* att_src = (const float*)d_in[4];
    const float* att_dst = (const float*)d_in[5];
    const float* bias = (const float*)d_in[6];
    const float* ln_g = (const float*)d_in[7];
    const float* ln_b = (const float*)d_in[8];
    const float* W1 = (const float*)d_in[9];
    const float* b1 = (const float*)d_in[10];
    const float* W2 = (const float*)d_in[11];
    const float* b2 = (const float*)d_in[12];

    const int N = in_sizes[0] / DD;
    const int E = in_sizes[1] / 2;

    // workspace carve-up
    char* p = (char*)d_ws;
    auto carve = [&](size_t bytes) {
        char* r = p;
        p += (bytes + 255) & ~(size_t)255;
        return r;
    };
    unsigned short* x_bf = (unsigned short*)carve((size_t)N * DD * 2);
    unsigned short* xp_bf = (unsigned short*)carve((size_t)N * DD * 2);
    unsigned short* hn_bf = (unsigned short*)carve((size_t)N * DD * 2);
    float* a_src = (float*)carve((size_t)N * H * 4);
    float* a_dst = (float*)carve((size_t)N * H * 4);
    int* gc = (int*)carve(NBMAX * 4);                       // bucket totals
    int* bb = (int*)carve(NBMAX * 4);                       // bucket bases
    int* rowPtr = (int*)carve((size_t)N * 4);
    int* cnt = (int*)carve((size_t)N * 4);
    unsigned int* tmp = (unsigned int*)carve((size_t)E * 4); // bucket-grouped packed
    int* src_sorted = (int*)carve((size_t)E * 4);            // compact CSR payload
    int* blockBase = (int*)carve((size_t)((E + EPB - 1) / EPB) * NBMAX * 4);
    unsigned short* Wt = (unsigned short*)carve(65536 * 2);
    unsigned short* W1t = (unsigned short*)carve(65536 * 2);
    unsigned short* W2t = (unsigned short*)carve(65536 * 2);

    const int n4 = N * DD / 4;
    const int SB = (E + EPB - 1) / EPB;      // sort blocks (196)
    const int NB = (N + 255) >> 8;           // dest buckets (196)

    // 0. zero bucket counters
    zero_gc<<<1, 256, 0, stream>>>(gc);

    // 1. prep: S1 coarse-hist (first) + weight transposes + x->bf16
    int prep_blocks = SB + 768 + (n4 + 255) / 256;
    prep<<<prep_blocks, 256, 0, stream>>>(x, x_bf, W, Wt, W1, W1t, W2, W2t,
                                          edge_index, gc, blockBase, N, n4, E, SB);

    // 2-4. counting sort: scan buckets, bucket-scatter, per-bucket dest-CSR
    scan_gc<<<1, 64, 0, stream>>>(gc, bb);
    bucket_scatter<<<SB, 256, 0, stream>>>(edge_index, bb, blockBase, tmp, E);
    bucket_csr<<<NB, 256, 0, stream>>>(tmp, bb, gc, src_sorted, rowPtr, cnt, N);

    const int gblocks = (N + 63) / 64;

    // 5. xp = x @ W (bf16 out) + fused attention scores  (barrier-free K-loop)
    gemm_fused<true, false><<<gblocks, 256, 0, stream>>>(
        x_bf, Wt, nullptr, nullptr, nullptr, xp_bf, N, att_src, att_dst, a_src, a_dst);

    // 6. fused aggregate + LN (bf16 out, compact CSR)
    aggregate_ln<<<(N + 3) / 4, 256, 0, stream>>>(xp_bf, x_bf, a_src, a_dst, rowPtr, cnt,
                                                  src_sorted, bias, ln_g, ln_b, hn_bf, N);

    // 7. fused FFN: out = relu(hn@W1+b1)@W2 + b2
    gemm_fused<false, true><<<gblocks, 256, 0, stream>>>(
        hn_bf, W1t, b1, W2t, b2, d_out, N, nullptr, nullptr, nullptr, nullptr);
}